// Round 11
// baseline (3086.546 us; speedup 1.0000x reference)
//
#include <hip/hip_runtime.h>
#include <hip/hip_bf16.h>
#include <math.h>

// B=4, N=512, T=288, L=128
#define NN 512
#define NT 288

#define REP_QSTAGE 32
#define REP_QMAIN  16
#define REP_PG1    16
#define REP_QRED   128

// ---------------------------------------------------------------------------
// Kernel T: weight re-layout (unchanged from R10).
// ---------------------------------------------------------------------------
__global__ __launch_bounds__(256) void kT(
    const float* __restrict__ W1, const float* __restrict__ W2,
    const float* __restrict__ Wp,
    float* __restrict__ Wt2, float* __restrict__ Wpt2)
{
    int g = blockIdx.x * 256 + threadIdx.x;
    if (g < 73728) {
        int k4 = g >> 10, col = (g >> 2) & 255, d = g & 3;
        int k = k4 * 4 + d;
        Wt2[g] = (col < 128) ? W1[col * 288 + k] : W2[(col - 128) * 288 + k];
    } else {
        int h = g - 73728;
        int k4 = h >> 10, col = (h >> 2) & 255, d = h & 3;
        int k = k4 * 4 + d;
        Wpt2[h] = (col < 128) ? Wp[col * 256 + k]
                              : Wp[(col - 128) * 256 + 128 + k];
    }
}

// ---------------------------------------------------------------------------
// Kernel P: unchanged from R10 (scalar-path x, Wt2/Wpt2 weights).
// ---------------------------------------------------------------------------
__global__ __launch_bounds__(512) void kP(
    const float* __restrict__ x,     // [2048][288]
    const float* __restrict__ Wt2,   // [72][256][4]
    const float* __restrict__ b1,    // [128]
    const float* __restrict__ b2,    // [128]
    const float* __restrict__ Wpt2,  // [32][256][4]
    const float* __restrict__ bp,    // [128]
    const float* __restrict__ Wb,    // [128]
    const float* __restrict__ bb,    // [1]
    float* __restrict__ S12,         // ws [2048][256]
    float* __restrict__ Aarr,        // ws [2048]
    float* __restrict__ Carr,        // ws [2048]
    float* __restrict__ x12g)        // ws scratch [2048][256]
{
    __shared__ __align__(16) float ph[8 * 256];
    __shared__ __align__(16) float s12s[8 * 257];

    const int t   = threadIdx.x;
    const int bn0 = blockIdx.x * 8;
    const int col = t & 255;
    const int kh  = t >> 8;

    const int kb1 = __builtin_amdgcn_readfirstlane(kh * 144);
    const float* xu  = x + (size_t)bn0 * NT;
    const float* wtb = Wt2 + (size_t)(kh * 36) * 1024 + col * 4;

    float acc[8];
#pragma unroll
    for (int n = 0; n < 8; ++n) acc[n] = 0.0f;

#pragma unroll 2
    for (int k4 = 0; k4 < 36; ++k4) {
        float4 w = *(const float4*)&wtb[k4 * 1024];
#pragma unroll
        for (int n = 0; n < 8; ++n) {
            float4 xv = *(const float4*)&xu[n * NT + kb1 + k4 * 4];
            acc[n] = fmaf(w.x, xv.x, acc[n]);
            acc[n] = fmaf(w.y, xv.y, acc[n]);
            acc[n] = fmaf(w.z, xv.z, acc[n]);
            acc[n] = fmaf(w.w, xv.w, acc[n]);
        }
    }

    const float bias1 = (col < 128) ? b1[col] : b2[col - 128];
    if (kh) {
#pragma unroll
        for (int n = 0; n < 8; ++n) ph[n * 256 + col] = acc[n];
    }
    __syncthreads();
    if (!kh) {
#pragma unroll
        for (int n = 0; n < 8; ++n) {
            float v = acc[n] + ph[n * 256 + col] + bias1;
            x12g[(size_t)(bn0 + n) * 256 + col] = fmaxf(v, 0.2f * v);
        }
    }
    __syncthreads();

    const int kb2 = __builtin_amdgcn_readfirstlane(((col < 128) ? 0 : 128) + kh * 64);
    const float* x2u = x12g + (size_t)bn0 * 256;
    const float* wpb = Wpt2 + (size_t)(kh * 16) * 1024 + col * 4;
    const float bias2 = (col < 128) ? bp[col] : 0.0f;

    float acc2[8];
#pragma unroll
    for (int n = 0; n < 8; ++n) acc2[n] = 0.0f;

#pragma unroll 2
    for (int k4 = 0; k4 < 16; ++k4) {
        float4 w = *(const float4*)&wpb[k4 * 1024];
#pragma unroll
        for (int n = 0; n < 8; ++n) {
            float4 xv = *(const float4*)&x2u[n * 256 + kb2 + k4 * 4];
            acc2[n] = fmaf(w.x, xv.x, acc2[n]);
            acc2[n] = fmaf(w.y, xv.y, acc2[n]);
            acc2[n] = fmaf(w.z, xv.z, acc2[n]);
            acc2[n] = fmaf(w.w, xv.w, acc2[n]);
        }
    }
    if (kh) {
#pragma unroll
        for (int n = 0; n < 8; ++n) ph[n * 256 + col] = acc2[n];
    }
    __syncthreads();

    if (!kh) {
#pragma unroll
        for (int n = 0; n < 8; ++n) {
            float sv = acc2[n] + ph[n * 256 + col] + bias2;
            S12[(size_t)(bn0 + n) * 256 + col] = sv;
            s12s[n * 257 + col] = sv;
        }
    }
    __syncthreads();

    {
        int lane32 = t & 31;
        int n = (t >> 5) & 7;
        int isC = t >> 8;
        int base = isC ? 128 : 0;
        float sum = 0.0f;
#pragma unroll
        for (int s = 0; s < 4; ++s) {
            int j = lane32 + s * 32;
            sum = fmaf(s12s[n * 257 + base + j], Wb[j], sum);
        }
#pragma unroll
        for (int m = 16; m >= 1; m >>= 1)
            sum += __shfl_xor(sum, m, 32);
        if (lane32 == 0) {
            if (isC) Carr[bn0 + n] = 0.6f * sum;
            else     Aarr[bn0 + n] = 0.6f * sum + bb[0];
        }
    }
}

// ---------------------------------------------------------------------------
// Kernel Q: unchanged from R10 (1024 threads, fused F).
// ---------------------------------------------------------------------------
__global__ __launch_bounds__(1024) void kQ(
    const float* __restrict__ S12,
    const float* __restrict__ Aarr,
    const float* __restrict__ Carr,
    const float* __restrict__ Wb,
    const float* __restrict__ noise,
    float* __restrict__ out)
{
    __shared__ __align__(16) float smem[32768];
    float* S1t = smem;
    float* S2t = smem + 16384;

    const int t = threadIdx.x;
    const int bx = blockIdx.x, by = blockIdx.y;

#pragma unroll
    for (int q = 0; q < 8; ++q) {
        int task = q * 1024 + t;
        int isS2 = task >> 12;
        int r    = task & 4095;
        int bz   = r >> 10;
        int row  = (r >> 5) & 31;
        int c4   = r & 31;
        size_t src = (size_t)(bz * NN + (isS2 ? by : bx) * 32 + row) * 256
                     + (isS2 ? 128 : 0) + c4 * 4;
        float4 v = *(const float4*)&S12[src];
        float* dst = (isS2 ? S2t : S1t) + bz * 4096;
        int rw = row ^ ((c4 & 7) << 2);
        dst[(c4 * 4 + 0) * 32 + rw] = v.x;
        dst[(c4 * 4 + 1) * 32 + rw] = v.y;
        dst[(c4 * 4 + 2) * 32 + rw] = v.z;
        dst[(c4 * 4 + 3) * 32 + rw] = v.w;
    }
    __syncthreads();

    const int lq = t >> 8;
    const int bz = (t >> 6) & 3;
    const int s  = t & 63;
    const int i0 = (s >> 3) << 2, j0 = (s & 7) << 2;

    const float* S1b = S1t + bz * 4096 + lq * 32 * 32;
    const float* S2b = S2t + bz * 4096 + lq * 32 * 32;
    const float* wbp = Wb + lq * 32;

    float accv[16];
#pragma unroll
    for (int k = 0; k < 16; ++k) accv[k] = 0.0f;

    for (int l4 = 0; l4 < 8; ++l4) {
        const int sw = (l4 & 7) << 2;
        const int lrow = l4 * 4 * 32;
        float4 wv = *(const float4*)&wbp[l4 * 4];
        const float wl[4] = {wv.x, wv.y, wv.z, wv.w};
#pragma unroll
        for (int d = 0; d < 4; ++d) {
            float4 a = *(const float4*)&S1b[lrow + d * 32 + (i0 ^ sw)];
            float4 b = *(const float4*)&S2b[lrow + d * 32 + (j0 ^ sw)];
            float w = wl[d];
            float ai[4] = {a.x, a.y, a.z, a.w};
            float bj[4] = {b.x, b.y, b.z, b.w};
#pragma unroll
            for (int ii = 0; ii < 4; ++ii)
#pragma unroll
                for (int jj = 0; jj < 4; ++jj) {
                    float tv = ai[ii] + bj[jj];
                    accv[ii * 4 + jj] = fmaf(fabsf(tv), w, accv[ii * 4 + jj]);
                }
        }
    }

    float* red = smem;
    const int tid2 = t & 255;
    __syncthreads();
    if (lq) {
#pragma unroll
        for (int q = 0; q < 4; ++q) {
            float4 v = {accv[4 * q], accv[4 * q + 1], accv[4 * q + 2], accv[4 * q + 3]};
            *(float4*)&red[(lq - 1) * 4096 + q * 1024 + tid2 * 4] = v;
        }
    }
    __syncthreads();

    float sig[16];
    float* redB = smem + 12288;
    if (!lq) {
#pragma unroll
        for (int p = 0; p < 3; ++p)
#pragma unroll
            for (int q = 0; q < 4; ++q) {
                float4 v = *(const float4*)&red[p * 4096 + q * 1024 + tid2 * 4];
                accv[4 * q]     += v.x;
                accv[4 * q + 1] += v.y;
                accv[4 * q + 2] += v.z;
                accv[4 * q + 3] += v.w;
            }
        float Av[4], Cv[4];
#pragma unroll
        for (int ii = 0; ii < 4; ++ii) Av[ii] = Aarr[bz * NN + bx * 32 + i0 + ii];
#pragma unroll
        for (int jj = 0; jj < 4; ++jj) Cv[jj] = Carr[bz * NN + by * 32 + j0 + jj];
#pragma unroll
        for (int ii = 0; ii < 4; ++ii)
#pragma unroll
            for (int jj = 0; jj < 4; ++jj) {
                float lg = Av[ii] + Cv[jj] + 0.4f * accv[ii * 4 + jj];
                sig[ii * 4 + jj] = 1.0f / (1.0f + expf(-lg));
            }
        if (bz) {
#pragma unroll
            for (int q = 0; q < 4; ++q) {
                float4 v = {sig[4 * q], sig[4 * q + 1], sig[4 * q + 2], sig[4 * q + 3]};
                *(float4*)&redB[(bz - 1) * 1024 + q * 256 + s * 4] = v;
            }
        }
    }
    __syncthreads();

    float* redP = smem + 15360;
    if (t < 64) {
#pragma unroll
        for (int bzz = 0; bzz < 3; ++bzz)
#pragma unroll
            for (int q = 0; q < 4; ++q) {
                float4 v = *(const float4*)&redB[bzz * 1024 + q * 256 + t * 4];
                sig[4 * q]     += v.x;
                sig[4 * q + 1] += v.y;
                sig[4 * q + 2] += v.z;
                sig[4 * q + 3] += v.w;
            }
#pragma unroll
        for (int q = 0; q < 4; ++q) {
            float4 v = {sig[4 * q], sig[4 * q + 1], sig[4 * q + 2], sig[4 * q + 3]};
            *(float4*)&redP[t * 16 + q * 4] = v;
        }
    }
    __syncthreads();

    if (t < 256) {
        int i   = t >> 3;
        int j0f = (t & 7) * 4;
        int sP  = (t >> 5) * 8 + (t & 7);
        int k0  = ((t >> 3) & 3) * 4;
        float4 pv4 = *(const float4*)&redP[sP * 16 + k0];
        float pv[4] = {pv4.x, pv4.y, pv4.z, pv4.w};

        int gi = bx * 32 + i;
        size_t base = (size_t)gi * NN + by * 32 + j0f;
        float4 nz = *(const float4*)&noise[base];
        float nv[4] = {nz.x, nz.y, nz.z, nz.w};

        float4 o;
        float* op = (float*)&o;
#pragma unroll
        for (int c = 0; c < 4; ++c) {
            float p = 0.25f * pv[c];
            int gj = by * 32 + j0f + c;
            if (gj == gi) p = 0.0f;
            float lp = logf(p + 1e-10f) - log1pf(-p + 1e-10f);
            lp = fminf(fmaxf(lp, -10.0f), 10.0f);
            float lgs = logf(nv[c]) - log1pf(-nv[c]);
            op[c] = 1.0f / (1.0f + expf(-(lp + lgs) * 5.0f));
        }
        *(float4*)&out[base] = o;
    }
}

// ===========================================================================
// ATTRIBUTION PROBES (write only to dead ws scratch; deterministic).
// Each repeats one phase REP times so its dispatch exceeds the ~39.6 us
// harness fills and surfaces in the top-5 counter rows.
// ===========================================================================

// ---- probe 1: kQ staging + barrier, x REP_QSTAGE ----
__global__ __launch_bounds__(1024) void pQstage(
    const float* __restrict__ S12, float* __restrict__ sink)
{
    __shared__ __align__(16) float smem[32768];
    float* S1t = smem;
    float* S2t = smem + 16384;
    const int t = threadIdx.x;
    const int bx = blockIdx.x, by = blockIdx.y;

    for (int r = 0; r < REP_QSTAGE; ++r) {
#pragma unroll
        for (int q = 0; q < 8; ++q) {
            int task = q * 1024 + t;
            int isS2 = task >> 12;
            int rr   = task & 4095;
            int bz   = rr >> 10;
            int row  = (rr >> 5) & 31;
            int c4   = rr & 31;
            size_t src = (size_t)(bz * NN + (isS2 ? by : bx) * 32 + row) * 256
                         + (isS2 ? 128 : 0) + c4 * 4;
            float4 v = *(const float4*)&S12[src];
            float* dst = (isS2 ? S2t : S1t) + bz * 4096;
            int rw = row ^ ((c4 & 7) << 2);
            dst[(c4 * 4 + 0) * 32 + rw] = v.x;
            dst[(c4 * 4 + 1) * 32 + rw] = v.y;
            dst[(c4 * 4 + 2) * 32 + rw] = v.z;
            dst[(c4 * 4 + 3) * 32 + rw] = v.w;
        }
        __syncthreads();
    }
    sink[(size_t)(by * 16 + bx) * 1024 + t] = S1t[t * 16] + S2t[t * 16 + 1];
}

// ---- probe 2: kQ main l4-loop, x REP_QMAIN (stage once first) ----
__global__ __launch_bounds__(1024) void pQmain(
    const float* __restrict__ S12, const float* __restrict__ Wb,
    float* __restrict__ sink)
{
    __shared__ __align__(16) float smem[32768];
    float* S1t = smem;
    float* S2t = smem + 16384;
    const int t = threadIdx.x;
    const int bx = blockIdx.x, by = blockIdx.y;

#pragma unroll
    for (int q = 0; q < 8; ++q) {
        int task = q * 1024 + t;
        int isS2 = task >> 12;
        int rr   = task & 4095;
        int bz   = rr >> 10;
        int row  = (rr >> 5) & 31;
        int c4   = rr & 31;
        size_t src = (size_t)(bz * NN + (isS2 ? by : bx) * 32 + row) * 256
                     + (isS2 ? 128 : 0) + c4 * 4;
        float4 v = *(const float4*)&S12[src];
        float* dst = (isS2 ? S2t : S1t) + bz * 4096;
        int rw = row ^ ((c4 & 7) << 2);
        dst[(c4 * 4 + 0) * 32 + rw] = v.x;
        dst[(c4 * 4 + 1) * 32 + rw] = v.y;
        dst[(c4 * 4 + 2) * 32 + rw] = v.z;
        dst[(c4 * 4 + 3) * 32 + rw] = v.w;
    }
    __syncthreads();

    const int lq = t >> 8;
    const int bz = (t >> 6) & 3;
    const int s  = t & 63;
    const int i0 = (s >> 3) << 2, j0 = (s & 7) << 2;
    const float* S1b = S1t + bz * 4096 + lq * 32 * 32;
    const float* S2b = S2t + bz * 4096 + lq * 32 * 32;
    const float* wbp = Wb + lq * 32;

    float accv[16];
#pragma unroll
    for (int k = 0; k < 16; ++k) accv[k] = 0.0f;

    for (int r = 0; r < REP_QMAIN; ++r) {
        for (int l4 = 0; l4 < 8; ++l4) {
            const int sw = (l4 & 7) << 2;
            const int lrow = l4 * 4 * 32;
            float4 wv = *(const float4*)&wbp[l4 * 4];
            const float wl[4] = {wv.x, wv.y, wv.z, wv.w};
#pragma unroll
            for (int d = 0; d < 4; ++d) {
                float4 a = *(const float4*)&S1b[lrow + d * 32 + (i0 ^ sw)];
                float4 b = *(const float4*)&S2b[lrow + d * 32 + (j0 ^ sw)];
                float w = wl[d];
                float ai[4] = {a.x, a.y, a.z, a.w};
                float bj[4] = {b.x, b.y, b.z, b.w};
#pragma unroll
                for (int ii = 0; ii < 4; ++ii)
#pragma unroll
                    for (int jj = 0; jj < 4; ++jj) {
                        float tv = ai[ii] + bj[jj];
                        accv[ii * 4 + jj] = fmaf(fabsf(tv), w, accv[ii * 4 + jj]);
                    }
            }
        }
    }
    float* sb = sink + ((size_t)(by * 16 + bx) * 1024 + t) * 16;
#pragma unroll
    for (int k = 0; k < 16; ++k) sb[k] = accv[k];
}

// ---- probe 3: kP G1 GEMM loop, x REP_PG1 ----
__global__ __launch_bounds__(512) void pPg1(
    const float* __restrict__ x, const float* __restrict__ Wt2,
    float* __restrict__ sink)
{
    const int t   = threadIdx.x;
    const int bn0 = blockIdx.x * 8;
    const int col = t & 255;
    const int kh  = t >> 8;

    const int kb1 = __builtin_amdgcn_readfirstlane(kh * 144);
    const float* xu  = x + (size_t)bn0 * NT;
    const float* wtb = Wt2 + (size_t)(kh * 36) * 1024 + col * 4;

    float acc[8];
#pragma unroll
    for (int n = 0; n < 8; ++n) acc[n] = 0.0f;

    for (int r = 0; r < REP_PG1; ++r) {
#pragma unroll 2
        for (int k4 = 0; k4 < 36; ++k4) {
            float4 w = *(const float4*)&wtb[k4 * 1024];
#pragma unroll
            for (int n = 0; n < 8; ++n) {
                float4 xv = *(const float4*)&xu[n * NT + kb1 + k4 * 4];
                acc[n] = fmaf(w.x, xv.x, acc[n]);
                acc[n] = fmaf(w.y, xv.y, acc[n]);
                acc[n] = fmaf(w.z, xv.z, acc[n]);
                acc[n] = fmaf(w.w, xv.w, acc[n]);
            }
        }
    }
    float* sb = sink + ((size_t)blockIdx.x * 512 + t) * 8;
#pragma unroll
    for (int n = 0; n < 8; ++n) sb[n] = acc[n];
}

// ---- probe 4: kQ reduction+sigmoid+F chain, x REP_QRED ----
__global__ __launch_bounds__(1024) void pQred(
    const float* __restrict__ Aarr, const float* __restrict__ Carr,
    const float* __restrict__ noise, float* __restrict__ sink)
{
    __shared__ __align__(16) float smem[32768];
    const int t = threadIdx.x;
    const int bx = blockIdx.x, by = blockIdx.y;
    const int lq = t >> 8;
    const int bz = (t >> 6) & 3;
    const int s  = t & 63;
    const int i0 = (s >> 3) << 2, j0 = (s & 7) << 2;
    const int tid2 = t & 255;

    float accv[16];
#pragma unroll
    for (int k = 0; k < 16; ++k) accv[k] = (float)(tid2 & 15) * 0.01f + k * 0.1f;

    float osum = 0.0f;
    float* red  = smem;
    float* redB = smem + 12288;
    float* redP = smem + 15360;

    for (int r = 0; r < REP_QRED; ++r) {
        __syncthreads();
        if (lq) {
#pragma unroll
            for (int q = 0; q < 4; ++q) {
                float4 v = {accv[4 * q], accv[4 * q + 1], accv[4 * q + 2], accv[4 * q + 3]};
                *(float4*)&red[(lq - 1) * 4096 + q * 1024 + tid2 * 4] = v;
            }
        }
        __syncthreads();
        float sig[16];
        if (!lq) {
            float tmp[16];
#pragma unroll
            for (int k = 0; k < 16; ++k) tmp[k] = accv[k];
#pragma unroll
            for (int p = 0; p < 3; ++p)
#pragma unroll
                for (int q = 0; q < 4; ++q) {
                    float4 v = *(const float4*)&red[p * 4096 + q * 1024 + tid2 * 4];
                    tmp[4 * q]     += v.x;
                    tmp[4 * q + 1] += v.y;
                    tmp[4 * q + 2] += v.z;
                    tmp[4 * q + 3] += v.w;
                }
            float Av[4], Cv[4];
#pragma unroll
            for (int ii = 0; ii < 4; ++ii) Av[ii] = Aarr[bz * NN + bx * 32 + i0 + ii];
#pragma unroll
            for (int jj = 0; jj < 4; ++jj) Cv[jj] = Carr[bz * NN + by * 32 + j0 + jj];
#pragma unroll
            for (int ii = 0; ii < 4; ++ii)
#pragma unroll
                for (int jj = 0; jj < 4; ++jj) {
                    float lg = Av[ii] + Cv[jj] + 0.4f * tmp[ii * 4 + jj];
                    sig[ii * 4 + jj] = 1.0f / (1.0f + expf(-lg));
                }
            if (bz) {
#pragma unroll
                for (int q = 0; q < 4; ++q) {
                    float4 v = {sig[4 * q], sig[4 * q + 1], sig[4 * q + 2], sig[4 * q + 3]};
                    *(float4*)&redB[(bz - 1) * 1024 + q * 256 + s * 4] = v;
                }
            }
        }
        __syncthreads();
        if (t < 64) {
#pragma unroll
            for (int bzz = 0; bzz < 3; ++bzz)
#pragma unroll
                for (int q = 0; q < 4; ++q) {
                    float4 v = *(const float4*)&redB[bzz * 1024 + q * 256 + t * 4];
                    sig[4 * q]     += v.x;
                    sig[4 * q + 1] += v.y;
                    sig[4 * q + 2] += v.z;
                    sig[4 * q + 3] += v.w;
                }
#pragma unroll
            for (int q = 0; q < 4; ++q) {
                float4 v = {sig[4 * q], sig[4 * q + 1], sig[4 * q + 2], sig[4 * q + 3]};
                *(float4*)&redP[t * 16 + q * 4] = v;
            }
        }
        __syncthreads();
        if (t < 256) {
            int i   = t >> 3;
            int j0f = (t & 7) * 4;
            int sP  = (t >> 5) * 8 + (t & 7);
            int k0  = ((t >> 3) & 3) * 4;
            float4 pv4 = *(const float4*)&redP[sP * 16 + k0];
            float pv[4] = {pv4.x, pv4.y, pv4.z, pv4.w};
            int gi = bx * 32 + i;
            size_t base = (size_t)gi * NN + by * 32 + j0f;
            float4 nz = *(const float4*)&noise[base];
            float nv[4] = {nz.x, nz.y, nz.z, nz.w};
#pragma unroll
            for (int c = 0; c < 4; ++c) {
                float p = 0.25f * pv[c];
                int gj = by * 32 + j0f + c;
                if (gj == gi) p = 0.0f;
                float lp = logf(p + 1e-10f) - log1pf(-p + 1e-10f);
                lp = fminf(fmaxf(lp, -10.0f), 10.0f);
                float lgs = logf(nv[c]) - log1pf(-nv[c]);
                osum += 1.0f / (1.0f + expf(-(lp + lgs) * 5.0f));
            }
        }
    }
    if (t < 256)
        sink[(size_t)(by * 16 + bx) * 256 + t] = osum;
}

// ---------------------------------------------------------------------------
extern "C" void kernel_launch(void* const* d_in, const int* in_sizes, int n_in,
                              void* d_out, int out_size, void* d_ws, size_t ws_size,
                              hipStream_t stream) {
    const float* x     = (const float*)d_in[0];
    const float* W1    = (const float*)d_in[1];
    const float* b1    = (const float*)d_in[2];
    const float* W2    = (const float*)d_in[3];
    const float* b2    = (const float*)d_in[4];
    const float* Wp    = (const float*)d_in[5];
    const float* bp    = (const float*)d_in[6];
    const float* Wb    = (const float*)d_in[7];
    const float* bb    = (const float*)d_in[8];
    const float* noise = (const float*)d_in[9];

    float* ws    = (float*)d_ws;
    float* S12   = ws;                    // 524288
    float* Aarr  = ws + 524288;           // 2048
    float* Carr  = Aarr + 2048;           // 2048
    float* Wt2   = Carr + 2048;           // 73728
    float* Wpt2  = Wt2 + 73728;           // 32768
    float* x12g  = Wpt2 + 32768;          // 524288
    float* sinkA = x12g + 524288;         // 262144
    float* sinkB = sinkA + 262144;        // 4194304
    float* sinkC = sinkB + 4194304;       // 1048576
    float* sinkD = sinkC + 1048576;       // 65536

    kT<<<416, 256, 0, stream>>>(W1, W2, Wp, Wt2, Wpt2);
    kP<<<256, 512, 0, stream>>>(x, Wt2, b1, b2, Wpt2, bp, Wb, bb,
                                S12, Aarr, Carr, x12g);
    kQ<<<dim3(16, 16), 1024, 0, stream>>>(S12, Aarr, Carr, Wb, noise,
                                          (float*)d_out);

    // ---- attribution probes (dead-ws sinks; do not affect d_out) ----
    pQstage<<<dim3(16, 16), 1024, 0, stream>>>(S12, sinkA);
    pQmain <<<dim3(16, 16), 1024, 0, stream>>>(S12, Wb, sinkB);
    pPg1   <<<256, 512, 0, stream>>>(x, Wt2, sinkC);
    pQred  <<<dim3(16, 16), 1024, 0, stream>>>(Aarr, Carr, noise, sinkD);
}

// Round 12
// 169.431 us; speedup vs baseline: 18.2171x; 18.2171x over previous
//
#include <hip/hip_runtime.h>
#include <hip/hip_bf16.h>
#include <math.h>

// B=4, N=512, T=288, L=128
#define NN 512
#define NT 288

#define REP_P 4
#define REP_Q 4

// ---------------------------------------------------------------------------
// Kernel P: EXACT R7/R6 structure (proven 43.6 us config), whole body wrapped
// in a REP_P loop (idempotent: same values written every iteration).
// #pragma unroll 1 + per-iter memory clobber => codegen identical to REP=1,
// dispatch runs 4x longer => surfaces in top-5 with production counters.
// ---------------------------------------------------------------------------
__global__ __launch_bounds__(512) void kP(
    const float* __restrict__ x,   // [2048][288]
    const float* __restrict__ W1,  // [128][288]
    const float* __restrict__ b1,  // [128]
    const float* __restrict__ W2,  // [128][288]
    const float* __restrict__ b2,  // [128]
    const float* __restrict__ Wp,  // [128][256]
    const float* __restrict__ bp,  // [128]
    const float* __restrict__ Wb,  // [128]
    const float* __restrict__ bb,  // [1]
    float* __restrict__ S12,       // ws [2048][256]
    float* __restrict__ Aarr,      // ws [2048]
    float* __restrict__ Carr)      // ws [2048]
{
    __shared__ __align__(16) float xs[8 * NT];     // aliased s12s[8][257] later
    __shared__ __align__(16) float x12s[8 * 256];
    __shared__ __align__(16) float ph[8 * 256];

    const int t   = threadIdx.x;
    const int bn0 = blockIdx.x * 8;
    const int col = t & 255;
    const int kh  = t >> 8;

#pragma unroll 1
    for (int rep = 0; rep < REP_P; ++rep) {
        asm volatile("" ::: "memory");   // forbid load hoisting across reps

        // stage 8 x-rows (576 float4)
        for (int q = 0; q < 2; ++q) {
            int idx = q * 512 + t;
            if (idx < 576) {
                int row = idx / 72, c4 = idx % 72;
                *(float4*)&xs[row * NT + c4 * 4] =
                    *(const float4*)&x[(size_t)(bn0 + row) * NT + c4 * 4];
            }
        }
        __syncthreads();

        // G1: col of [x1|x2] for 8 rows; K=288 split 144/144 over kh
        const float* wrow = ((col < 128) ? (W1 + col * NT) : (W2 + (col - 128) * NT))
                            + kh * 144;
        const float bias1 = (col < 128) ? b1[col] : b2[col - 128];
        const int kb1 = kh * 144;

        float acc[8];
#pragma unroll
        for (int n = 0; n < 8; ++n) acc[n] = 0.0f;

        for (int k = 0; k < 144; k += 4) {
            float4 w = *(const float4*)(wrow + k);
#pragma unroll
            for (int n = 0; n < 8; ++n) {
                float4 xv = *(const float4*)&xs[n * NT + kb1 + k];
                acc[n] = fmaf(w.x, xv.x, acc[n]);
                acc[n] = fmaf(w.y, xv.y, acc[n]);
                acc[n] = fmaf(w.z, xv.z, acc[n]);
                acc[n] = fmaf(w.w, xv.w, acc[n]);
            }
        }
        if (kh) {
#pragma unroll
            for (int n = 0; n < 8; ++n) ph[n * 256 + col] = acc[n];
        }
        __syncthreads();
        if (!kh) {
#pragma unroll
            for (int n = 0; n < 8; ++n) {
                float v = acc[n] + ph[n * 256 + col] + bias1;
                x12s[n * 256 + col] = fmaxf(v, 0.2f * v);   // leaky
            }
        }
        __syncthreads();

        // G2: col of [S1|S2] for 8 rows; K=128 split 64/64 over kh
        const int koff = (col < 128) ? 0 : 128;
        const float* wprow = ((col < 128) ? (Wp + col * 256)
                                          : (Wp + (col - 128) * 256 + 128))
                             + kh * 64;
        const float bias2 = (col < 128) ? bp[col] : 0.0f;
        const int kb2 = koff + kh * 64;

        float acc2[8];
#pragma unroll
        for (int n = 0; n < 8; ++n) acc2[n] = 0.0f;

        for (int k = 0; k < 64; k += 4) {
            float4 w = *(const float4*)(wprow + k);
#pragma unroll
            for (int n = 0; n < 8; ++n) {
                float4 xv = *(const float4*)&x12s[n * 256 + kb2 + k];
                acc2[n] = fmaf(w.x, xv.x, acc2[n]);
                acc2[n] = fmaf(w.y, xv.y, acc2[n]);
                acc2[n] = fmaf(w.z, xv.z, acc2[n]);
                acc2[n] = fmaf(w.w, xv.w, acc2[n]);
            }
        }
        if (kh) {
#pragma unroll
            for (int n = 0; n < 8; ++n) ph[n * 256 + col] = acc2[n];
        }
        __syncthreads();

        float* s12s = xs;   // alias: xs dead after G1
        if (!kh) {
#pragma unroll
            for (int n = 0; n < 8; ++n) {
                float sv = acc2[n] + ph[n * 256 + col] + bias2;
                S12[(size_t)(bn0 + n) * 256 + col] = sv;
                s12s[n * 257 + col] = sv;
            }
        }
        __syncthreads();

        // per-row dots with Wb: 16 dots x 32 lanes
        {
            int lane32 = t & 31;
            int n = (t >> 5) & 7;
            int isC = t >> 8;
            int base = isC ? 128 : 0;
            float sum = 0.0f;
#pragma unroll
            for (int s = 0; s < 4; ++s) {
                int j = lane32 + s * 32;
                sum = fmaf(s12s[n * 257 + base + j], Wb[j], sum);
            }
#pragma unroll
            for (int m = 16; m >= 1; m >>= 1)
                sum += __shfl_xor(sum, m, 32);
            if (lane32 == 0) {
                if (isC) Carr[bn0 + n] = 0.6f * sum;
                else     Aarr[bn0 + n] = 0.6f * sum + bb[0];
            }
        }
        __syncthreads();   // xs re-staged next rep; s12s readers done
    }
}

// ---------------------------------------------------------------------------
// Kernel Q: EXACT R7 fused kernel (32x32 tile, 4 bz in-block, 512 threads),
// whole body wrapped in REP_Q loop (idempotent out-writes).
// ---------------------------------------------------------------------------
__global__ __launch_bounds__(512) void kQ(
    const float* __restrict__ S12,   // [2048][256]
    const float* __restrict__ Aarr,  // [2048]
    const float* __restrict__ Carr,  // [2048]
    const float* __restrict__ Wb,    // [128]
    const float* __restrict__ noise, // [512][512]
    float* __restrict__ out)         // [512][512]
{
    __shared__ __align__(16) float smem[32768];   // 128 KB
    float* S1t = smem;             // [4][128][32]
    float* S2t = smem + 16384;     // [4][128][32]

    const int t = threadIdx.x;
    const int bx = blockIdx.x, by = blockIdx.y;

#pragma unroll 1
    for (int rep = 0; rep < REP_Q; ++rep) {
        asm volatile("" ::: "memory");

        // stage all 4 bz tiles: 8192 float4 tasks, 16 per thread
#pragma unroll
        for (int q = 0; q < 16; ++q) {
            int task = q * 512 + t;
            int isS2 = task >> 12;
            int r    = task & 4095;
            int bz   = r >> 10;
            int row  = (r >> 5) & 31;
            int c4   = r & 31;
            size_t src = (size_t)(bz * NN + (isS2 ? by : bx) * 32 + row) * 256
                         + (isS2 ? 128 : 0) + c4 * 4;
            float4 v = *(const float4*)&S12[src];
            float* dst = (isS2 ? S2t : S1t) + bz * 4096;
            int rw = row ^ ((c4 & 7) << 2);
            dst[(c4 * 4 + 0) * 32 + rw] = v.x;
            dst[(c4 * 4 + 1) * 32 + rw] = v.y;
            dst[(c4 * 4 + 2) * 32 + rw] = v.z;
            dst[(c4 * 4 + 3) * 32 + rw] = v.w;
        }
        __syncthreads();

        const int lh = t >> 8;
        const int bz = (t >> 6) & 3;
        const int s  = t & 63;
        const int i0 = (s >> 3) << 2, j0 = (s & 7) << 2;

        const float* S1b = S1t + bz * 4096 + lh * 64 * 32;
        const float* S2b = S2t + bz * 4096 + lh * 64 * 32;
        const float* wbp = Wb + lh * 64;

        float accv[16];
#pragma unroll
        for (int k = 0; k < 16; ++k) accv[k] = 0.0f;

        for (int l4 = 0; l4 < 16; ++l4) {
            const int sw = (l4 & 7) << 2;
            const int lrow = l4 * 4 * 32;
            float4 wv = *(const float4*)&wbp[l4 * 4];
            const float wl[4] = {wv.x, wv.y, wv.z, wv.w};
#pragma unroll
            for (int d = 0; d < 4; ++d) {
                float4 a = *(const float4*)&S1b[lrow + d * 32 + (i0 ^ sw)];
                float4 b = *(const float4*)&S2b[lrow + d * 32 + (j0 ^ sw)];
                float w = wl[d];
                float ai[4] = {a.x, a.y, a.z, a.w};
                float bj[4] = {b.x, b.y, b.z, b.w};
#pragma unroll
                for (int ii = 0; ii < 4; ++ii)
#pragma unroll
                    for (int jj = 0; jj < 4; ++jj) {
                        float tv = ai[ii] + bj[jj];
                        accv[ii * 4 + jj] = fmaf(fabsf(tv), w, accv[ii * 4 + jj]);
                    }
            }
        }

        // reduce l-halves through LDS (alias dead S1t)
        float* red = smem;
        const int tid2 = t & 255;
        __syncthreads();
        if (lh) {
#pragma unroll
            for (int q = 0; q < 4; ++q) {
                float4 v = {accv[4 * q], accv[4 * q + 1],
                            accv[4 * q + 2], accv[4 * q + 3]};
                *(float4*)&red[q * 1024 + tid2 * 4] = v;
            }
        }
        __syncthreads();

        float sig[16];
        if (!lh) {
#pragma unroll
            for (int q = 0; q < 4; ++q) {
                float4 v = *(const float4*)&red[q * 1024 + tid2 * 4];
                accv[4 * q]     += v.x;
                accv[4 * q + 1] += v.y;
                accv[4 * q + 2] += v.z;
                accv[4 * q + 3] += v.w;
            }
            float Av[4], Cv[4];
#pragma unroll
            for (int ii = 0; ii < 4; ++ii) Av[ii] = Aarr[bz * NN + bx * 32 + i0 + ii];
#pragma unroll
            for (int jj = 0; jj < 4; ++jj) Cv[jj] = Carr[bz * NN + by * 32 + j0 + jj];
#pragma unroll
            for (int ii = 0; ii < 4; ++ii)
#pragma unroll
                for (int jj = 0; jj < 4; ++jj) {
                    float lg = Av[ii] + Cv[jj] + 0.4f * accv[ii * 4 + jj];
                    sig[ii * 4 + jj] = 1.0f / (1.0f + expf(-lg));
                }
            float* redB = smem + 4096;
            if (bz) {
#pragma unroll
                for (int q = 0; q < 4; ++q) {
                    float4 v = {sig[4 * q], sig[4 * q + 1],
                                sig[4 * q + 2], sig[4 * q + 3]};
                    *(float4*)&redB[(bz - 1) * 1024 + q * 256 + s * 4] = v;
                }
            }
        }
        __syncthreads();

        float* redB = smem + 4096;
        float* redP = smem + 7168;
        if (t < 64) {                          // lh=0, bz=0, s=t
#pragma unroll
            for (int bzz = 0; bzz < 3; ++bzz)
#pragma unroll
                for (int q = 0; q < 4; ++q) {
                    float4 v = *(const float4*)&redB[bzz * 1024 + q * 256 + t * 4];
                    sig[4 * q]     += v.x;
                    sig[4 * q + 1] += v.y;
                    sig[4 * q + 2] += v.z;
                    sig[4 * q + 3] += v.w;
                }
#pragma unroll
            for (int q = 0; q < 4; ++q) {
                float4 v = {sig[4 * q], sig[4 * q + 1],
                            sig[4 * q + 2], sig[4 * q + 3]};
                *(float4*)&redP[t * 16 + q * 4] = v;
            }
        }
        __syncthreads();

        // phase F: 256 threads, 4 outputs each
        if (t < 256) {
            int i   = t >> 3;
            int j0f = (t & 7) * 4;
            int sP  = (t >> 5) * 8 + (t & 7);
            int k0  = ((t >> 3) & 3) * 4;
            float4 pv4 = *(const float4*)&redP[sP * 16 + k0];
            float pv[4] = {pv4.x, pv4.y, pv4.z, pv4.w};

            int gi = bx * 32 + i;
            size_t base = (size_t)gi * NN + by * 32 + j0f;
            float4 nz = *(const float4*)&noise[base];
            float nv[4] = {nz.x, nz.y, nz.z, nz.w};

            float4 o;
            float* op = (float*)&o;
#pragma unroll
            for (int c = 0; c < 4; ++c) {
                float p = 0.25f * pv[c];
                int gj = by * 32 + j0f + c;
                if (gj == gi) p = 0.0f;
                float lp = logf(p + 1e-10f) - log1pf(-p + 1e-10f);
                lp = fminf(fmaxf(lp, -10.0f), 10.0f);
                float lgs = logf(nv[c]) - log1pf(-nv[c]);
                op[c] = 1.0f / (1.0f + expf(-(lp + lgs) * 5.0f));
            }
            *(float4*)&out[base] = o;
        }
        __syncthreads();   // redP read done before next rep re-stages S1t
    }
}

// ---------------------------------------------------------------------------
extern "C" void kernel_launch(void* const* d_in, const int* in_sizes, int n_in,
                              void* d_out, int out_size, void* d_ws, size_t ws_size,
                              hipStream_t stream) {
    const float* x     = (const float*)d_in[0];
    const float* W1    = (const float*)d_in[1];
    const float* b1    = (const float*)d_in[2];
    const float* W2    = (const float*)d_in[3];
    const float* b2    = (const float*)d_in[4];
    const float* Wp    = (const float*)d_in[5];
    const float* bp    = (const float*)d_in[6];
    const float* Wb    = (const float*)d_in[7];
    const float* bb    = (const float*)d_in[8];
    const float* noise = (const float*)d_in[9];

    float* ws   = (float*)d_ws;
    float* S12  = ws;                   // 524288 floats
    float* Aarr = ws + 524288;          // 2048
    float* Carr = Aarr + 2048;          // 2048

    kP<<<256, 512, 0, stream>>>(x, W1, b1, W2, b2, Wp, bp, Wb, bb,
                                S12, Aarr, Carr);
    kQ<<<dim3(16, 16), 512, 0, stream>>>(S12, Aarr, Carr, Wb, noise,
                                         (float*)d_out);
}

// Round 13
// 38.318 us; speedup vs baseline: 80.5506x; 4.4217x over previous
//
#include <hip/hip_runtime.h>
#include <hip/hip_bf16.h>
#include <math.h>

// B=4, N=512, T=288, L=128
#define NN 512
#define NT 288

// ---------------------------------------------------------------------------
// Kernel T: weight transpose (once per call, ~0.4 MB, L2-resident after).
// Wt[288][256]:  Wt[k][col]  = col<128 ? W1[col][k] : W2[col-128][k]
// Wpt[128][256]: Wpt[k][col] = col<128 ? Wp[col][k] : Wp[col-128][128+k]
// ---------------------------------------------------------------------------
__global__ __launch_bounds__(256) void kT(
    const float* __restrict__ W1, const float* __restrict__ W2,
    const float* __restrict__ Wp,
    float* __restrict__ Wt, float* __restrict__ Wpt)
{
    int g = blockIdx.x * 256 + threadIdx.x;
    if (g < 288 * 256) {
        int k = g >> 8, col = g & 255;
        Wt[g] = (col < 128) ? W1[col * 288 + k] : W2[(col - 128) * 288 + k];
    } else {
        int h = g - 288 * 256;          // 0 .. 32767
        int k = h >> 8, col = h & 255;
        Wpt[h] = (col < 128) ? Wp[col * 256 + k]
                             : Wp[(col - 128) * 256 + 128 + k];
    }
}

// ---------------------------------------------------------------------------
// Kernel P (restructured for 4x arithmetic intensity per feed instruction):
// 256 blocks x 512 threads = (c4 0..63, khe 0..7); thread computes 4 cols x
// 8 rows over K/8. Per wave: G1 72 (was 288) + G2 32 (was 128) broadcast
// ds_read_b128; W loads coalesced from transposed Wt/Wpt (1KB/instr, was
// 64 scattered lines). K-partials reduced via 56KB LDS ph buffer.
// ---------------------------------------------------------------------------
__global__ __launch_bounds__(512) void kP(
    const float* __restrict__ x,    // [2048][288]
    const float* __restrict__ Wt,   // [288][256]
    const float* __restrict__ b1,   // [128]
    const float* __restrict__ b2,   // [128]
    const float* __restrict__ Wpt,  // [128][256]
    const float* __restrict__ bp,   // [128]
    const float* __restrict__ Wb,   // [128]
    const float* __restrict__ bb,   // [1]
    float* __restrict__ S12,        // ws [2048][256]
    float* __restrict__ Aarr,       // ws [2048]
    float* __restrict__ Carr)       // ws [2048]
{
    __shared__ __align__(16) float xs[8 * NT];      // 9.2 KB
    __shared__ __align__(16) float x12s[8 * 256];   // 8 KB
    __shared__ __align__(16) float ph[7 * 2048];    // 57.3 KB
    __shared__ __align__(16) float s12s[8 * 260];   // 8.3 KB (260: f4-aligned rows)

    const int t   = threadIdx.x;
    const int bn0 = blockIdx.x * 8;
    const int c4  = t & 63;         // col quad: cols c4*4 .. +3
    const int khe = t >> 6;         // K-eighth, wave-uniform

    // stage 8 x-rows (576 float4)
    for (int q = 0; q < 2; ++q) {
        int idx = q * 512 + t;
        if (idx < 576) {
            int row = idx / 72, cc = idx % 72;
            *(float4*)&xs[row * NT + cc * 4] =
                *(const float4*)&x[(size_t)(bn0 + row) * NT + cc * 4];
        }
    }
    __syncthreads();

    // ---- G1: 4 cols x 8 rows, K=288 split in 8 x 36 over khe ----
    float acc[8][4];
#pragma unroll
    for (int n = 0; n < 8; ++n)
#pragma unroll
        for (int c = 0; c < 4; ++c) acc[n][c] = 0.0f;

    const int kbase1 = khe * 36;
#pragma unroll 2
    for (int k4 = 0; k4 < 9; ++k4) {
        const int k0 = kbase1 + k4 * 4;
        float4 w0 = *(const float4*)&Wt[(size_t)(k0 + 0) * 256 + c4 * 4];
        float4 w1 = *(const float4*)&Wt[(size_t)(k0 + 1) * 256 + c4 * 4];
        float4 w2 = *(const float4*)&Wt[(size_t)(k0 + 2) * 256 + c4 * 4];
        float4 w3 = *(const float4*)&Wt[(size_t)(k0 + 3) * 256 + c4 * 4];
        const float* w0p = (const float*)&w0;
        const float* w1p = (const float*)&w1;
        const float* w2p = (const float*)&w2;
        const float* w3p = (const float*)&w3;
#pragma unroll
        for (int n = 0; n < 8; ++n) {
            float4 xv = *(const float4*)&xs[n * NT + k0];   // broadcast
#pragma unroll
            for (int c = 0; c < 4; ++c) {
                acc[n][c] = fmaf(xv.x, w0p[c], acc[n][c]);
                acc[n][c] = fmaf(xv.y, w1p[c], acc[n][c]);
                acc[n][c] = fmaf(xv.z, w2p[c], acc[n][c]);
                acc[n][c] = fmaf(xv.w, w3p[c], acc[n][c]);
            }
        }
    }

    // reduce over khe through ph
    if (khe) {
#pragma unroll
        for (int n = 0; n < 8; ++n) {
            float4 v = {acc[n][0], acc[n][1], acc[n][2], acc[n][3]};
            *(float4*)&ph[(khe - 1) * 2048 + n * 256 + c4 * 4] = v;
        }
    }
    __syncthreads();
    if (!khe) {
        float4 bias4 = (c4 < 32) ? *(const float4*)&b1[c4 * 4]
                                 : *(const float4*)&b2[(c4 - 32) * 4];
        const float* bp4 = (const float*)&bias4;
#pragma unroll
        for (int n = 0; n < 8; ++n) {
            float s0 = acc[n][0], s1 = acc[n][1], s2 = acc[n][2], s3 = acc[n][3];
#pragma unroll
            for (int p = 0; p < 7; ++p) {
                float4 v = *(const float4*)&ph[p * 2048 + n * 256 + c4 * 4];
                s0 += v.x; s1 += v.y; s2 += v.z; s3 += v.w;
            }
            float4 r;
            float* rp = (float*)&r;
            float sv[4] = {s0, s1, s2, s3};
#pragma unroll
            for (int c = 0; c < 4; ++c) {
                float v = sv[c] + bp4[c];
                rp[c] = fmaxf(v, 0.2f * v);     // leaky
            }
            *(float4*)&x12s[n * 256 + c4 * 4] = r;
        }
    }
    __syncthreads();

    // ---- G2: 4 cols x 8 rows, K=128 split in 8 x 16 over khe ----
    float acc2[8][4];
#pragma unroll
    for (int n = 0; n < 8; ++n)
#pragma unroll
        for (int c = 0; c < 4; ++c) acc2[n][c] = 0.0f;

    const int koff = (c4 < 32) ? 0 : 128;   // x1 vs x2 side (per lane-half)
    const int kbase2 = khe * 16;
#pragma unroll 2
    for (int k4 = 0; k4 < 4; ++k4) {
        const int k0 = kbase2 + k4 * 4;
        float4 w0 = *(const float4*)&Wpt[(size_t)(k0 + 0) * 256 + c4 * 4];
        float4 w1 = *(const float4*)&Wpt[(size_t)(k0 + 1) * 256 + c4 * 4];
        float4 w2 = *(const float4*)&Wpt[(size_t)(k0 + 2) * 256 + c4 * 4];
        float4 w3 = *(const float4*)&Wpt[(size_t)(k0 + 3) * 256 + c4 * 4];
        const float* w0p = (const float*)&w0;
        const float* w1p = (const float*)&w1;
        const float* w2p = (const float*)&w2;
        const float* w3p = (const float*)&w3;
#pragma unroll
        for (int n = 0; n < 8; ++n) {
            float4 xv = *(const float4*)&x12s[n * 256 + koff + k0];  // 2-grp bcast
#pragma unroll
            for (int c = 0; c < 4; ++c) {
                acc2[n][c] = fmaf(xv.x, w0p[c], acc2[n][c]);
                acc2[n][c] = fmaf(xv.y, w1p[c], acc2[n][c]);
                acc2[n][c] = fmaf(xv.z, w2p[c], acc2[n][c]);
                acc2[n][c] = fmaf(xv.w, w3p[c], acc2[n][c]);
            }
        }
    }

    if (khe) {
#pragma unroll
        for (int n = 0; n < 8; ++n) {
            float4 v = {acc2[n][0], acc2[n][1], acc2[n][2], acc2[n][3]};
            *(float4*)&ph[(khe - 1) * 2048 + n * 256 + c4 * 4] = v;
        }
    }
    __syncthreads();
    if (!khe) {
        float4 bias4;
        if (c4 < 32) bias4 = *(const float4*)&bp[c4 * 4];
        else         bias4 = make_float4(0.f, 0.f, 0.f, 0.f);
        const float* bp4 = (const float*)&bias4;
#pragma unroll
        for (int n = 0; n < 8; ++n) {
            float s0 = acc2[n][0], s1 = acc2[n][1], s2 = acc2[n][2], s3 = acc2[n][3];
#pragma unroll
            for (int p = 0; p < 7; ++p) {
                float4 v = *(const float4*)&ph[p * 2048 + n * 256 + c4 * 4];
                s0 += v.x; s1 += v.y; s2 += v.z; s3 += v.w;
            }
            float sv[4] = {s0, s1, s2, s3};
            float4 r;
            float* rp = (float*)&r;
#pragma unroll
            for (int c = 0; c < 4; ++c) rp[c] = sv[c] + bp4[c];
            *(float4*)&S12[(size_t)(bn0 + n) * 256 + c4 * 4] = r;
            *(float4*)&s12s[n * 260 + c4 * 4] = r;
        }
    }
    __syncthreads();

    // ---- per-row dots with Wb: 16 dots x 32 lanes ----
    {
        int lane32 = t & 31;
        int n = (t >> 5) & 7;
        int isC = t >> 8;
        int base = isC ? 128 : 0;
        float sum = 0.0f;
#pragma unroll
        for (int s = 0; s < 4; ++s) {
            int j = lane32 + s * 32;
            sum = fmaf(s12s[n * 260 + base + j], Wb[j], sum);
        }
#pragma unroll
        for (int m = 16; m >= 1; m >>= 1)
            sum += __shfl_xor(sum, m, 32);
        if (lane32 == 0) {
            if (isC) Carr[bn0 + n] = 0.6f * sum;
            else     Aarr[bn0 + n] = 0.6f * sum + bb[0];
        }
    }
}

// ---------------------------------------------------------------------------
// Kernel Q: fully-fused pairwise + mean-over-b + phase F (R7-verified,
// measured 12.5 us/iter in R12 attribution). Unchanged.
// ---------------------------------------------------------------------------
__global__ __launch_bounds__(512) void kQ(
    const float* __restrict__ S12,   // [2048][256]
    const float* __restrict__ Aarr,  // [2048]
    const float* __restrict__ Carr,  // [2048]
    const float* __restrict__ Wb,    // [128]
    const float* __restrict__ noise, // [512][512]
    float* __restrict__ out)         // [512][512]
{
    __shared__ __align__(16) float smem[32768];   // 128 KB
    float* S1t = smem;             // [4][128][32]
    float* S2t = smem + 16384;     // [4][128][32]

    const int t = threadIdx.x;
    const int bx = blockIdx.x, by = blockIdx.y;

#pragma unroll
    for (int q = 0; q < 16; ++q) {
        int task = q * 512 + t;
        int isS2 = task >> 12;
        int r    = task & 4095;
        int bz   = r >> 10;
        int row  = (r >> 5) & 31;
        int c4   = r & 31;
        size_t src = (size_t)(bz * NN + (isS2 ? by : bx) * 32 + row) * 256
                     + (isS2 ? 128 : 0) + c4 * 4;
        float4 v = *(const float4*)&S12[src];
        float* dst = (isS2 ? S2t : S1t) + bz * 4096;
        int rw = row ^ ((c4 & 7) << 2);
        dst[(c4 * 4 + 0) * 32 + rw] = v.x;
        dst[(c4 * 4 + 1) * 32 + rw] = v.y;
        dst[(c4 * 4 + 2) * 32 + rw] = v.z;
        dst[(c4 * 4 + 3) * 32 + rw] = v.w;
    }
    __syncthreads();

    const int lh = t >> 8;
    const int bz = (t >> 6) & 3;
    const int s  = t & 63;
    const int i0 = (s >> 3) << 2, j0 = (s & 7) << 2;

    const float* S1b = S1t + bz * 4096 + lh * 64 * 32;
    const float* S2b = S2t + bz * 4096 + lh * 64 * 32;
    const float* wbp = Wb + lh * 64;

    float accv[16];
#pragma unroll
    for (int k = 0; k < 16; ++k) accv[k] = 0.0f;

    for (int l4 = 0; l4 < 16; ++l4) {
        const int sw = (l4 & 7) << 2;
        const int lrow = l4 * 4 * 32;
        float4 wv = *(const float4*)&wbp[l4 * 4];
        const float wl[4] = {wv.x, wv.y, wv.z, wv.w};
#pragma unroll
        for (int d = 0; d < 4; ++d) {
            float4 a = *(const float4*)&S1b[lrow + d * 32 + (i0 ^ sw)];
            float4 b = *(const float4*)&S2b[lrow + d * 32 + (j0 ^ sw)];
            float w = wl[d];
            float ai[4] = {a.x, a.y, a.z, a.w};
            float bj[4] = {b.x, b.y, b.z, b.w};
#pragma unroll
            for (int ii = 0; ii < 4; ++ii)
#pragma unroll
                for (int jj = 0; jj < 4; ++jj) {
                    float tv = ai[ii] + bj[jj];
                    accv[ii * 4 + jj] = fmaf(fabsf(tv), w, accv[ii * 4 + jj]);
                }
        }
    }

    float* red = smem;
    const int tid2 = t & 255;
    __syncthreads();
    if (lh) {
#pragma unroll
        for (int q = 0; q < 4; ++q) {
            float4 v = {accv[4 * q], accv[4 * q + 1], accv[4 * q + 2], accv[4 * q + 3]};
            *(float4*)&red[q * 1024 + tid2 * 4] = v;
        }
    }
    __syncthreads();

    float sig[16];
    if (!lh) {
#pragma unroll
        for (int q = 0; q < 4; ++q) {
            float4 v = *(const float4*)&red[q * 1024 + tid2 * 4];
            accv[4 * q]     += v.x;
            accv[4 * q + 1] += v.y;
            accv[4 * q + 2] += v.z;
            accv[4 * q + 3] += v.w;
        }
        float Av[4], Cv[4];
#pragma unroll
        for (int ii = 0; ii < 4; ++ii) Av[ii] = Aarr[bz * NN + bx * 32 + i0 + ii];
#pragma unroll
        for (int jj = 0; jj < 4; ++jj) Cv[jj] = Carr[bz * NN + by * 32 + j0 + jj];
#pragma unroll
        for (int ii = 0; ii < 4; ++ii)
#pragma unroll
            for (int jj = 0; jj < 4; ++jj) {
                float lg = Av[ii] + Cv[jj] + 0.4f * accv[ii * 4 + jj];
                sig[ii * 4 + jj] = 1.0f / (1.0f + expf(-lg));
            }
        float* redB = smem + 4096;
        if (bz) {
#pragma unroll
            for (int q = 0; q < 4; ++q) {
                float4 v = {sig[4 * q], sig[4 * q + 1], sig[4 * q + 2], sig[4 * q + 3]};
                *(float4*)&redB[(bz - 1) * 1024 + q * 256 + s * 4] = v;
            }
        }
    }
    __syncthreads();

    float* redB = smem + 4096;
    float* redP = smem + 7168;
    if (t < 64) {                          // lh=0, bz=0, s=t
#pragma unroll
        for (int bzz = 0; bzz < 3; ++bzz)
#pragma unroll
            for (int q = 0; q < 4; ++q) {
                float4 v = *(const float4*)&redB[bzz * 1024 + q * 256 + t * 4];
                sig[4 * q]     += v.x;
                sig[4 * q + 1] += v.y;
                sig[4 * q + 2] += v.z;
                sig[4 * q + 3] += v.w;
            }
#pragma unroll
        for (int q = 0; q < 4; ++q) {
            float4 v = {sig[4 * q], sig[4 * q + 1], sig[4 * q + 2], sig[4 * q + 3]};
            *(float4*)&redP[t * 16 + q * 4] = v;
        }
    }
    __syncthreads();

    if (t < 256) {
        int i   = t >> 3;
        int j0f = (t & 7) * 4;
        int sP  = (t >> 5) * 8 + (t & 7);
        int k0  = ((t >> 3) & 3) * 4;
        float4 pv4 = *(const float4*)&redP[sP * 16 + k0];
        float pv[4] = {pv4.x, pv4.y, pv4.z, pv4.w};

        int gi = bx * 32 + i;
        size_t base = (size_t)gi * NN + by * 32 + j0f;
        float4 nz = *(const float4*)&noise[base];
        float nv[4] = {nz.x, nz.y, nz.z, nz.w};

        float4 o;
        float* op = (float*)&o;
#pragma unroll
        for (int c = 0; c < 4; ++c) {
            float p = 0.25f * pv[c];
            int gj = by * 32 + j0f + c;
            if (gj == gi) p = 0.0f;
            float lp = logf(p + 1e-10f) - log1pf(-p + 1e-10f);
            lp = fminf(fmaxf(lp, -10.0f), 10.0f);
            float lgs = logf(nv[c]) - log1pf(-nv[c]);
            op[c] = 1.0f / (1.0f + expf(-(lp + lgs) * 5.0f));
        }
        *(float4*)&out[base] = o;
    }
}

// ---------------------------------------------------------------------------
extern "C" void kernel_launch(void* const* d_in, const int* in_sizes, int n_in,
                              void* d_out, int out_size, void* d_ws, size_t ws_size,
                              hipStream_t stream) {
    const float* x     = (const float*)d_in[0];
    const float* W1    = (const float*)d_in[1];
    const float* b1    = (const float*)d_in[2];
    const float* W2    = (const float*)d_in[3];
    const float* b2    = (const float*)d_in[4];
    const float* Wp    = (const float*)d_in[5];
    const float* bp    = (const float*)d_in[6];
    const float* Wb    = (const float*)d_in[7];
    const float* bb    = (const float*)d_in[8];
    const float* noise = (const float*)d_in[9];

    float* ws   = (float*)d_ws;
    float* S12  = ws;                   // 524288 floats
    float* Aarr = ws + 524288;          // 2048
    float* Carr = Aarr + 2048;          // 2048
    float* Wt   = Carr + 2048;          // 73728
    float* Wpt  = Wt + 73728;           // 32768

    kT<<<416, 256, 0, stream>>>(W1, W2, Wp, Wt, Wpt);
    kP<<<256, 512, 0, stream>>>(x, Wt, b1, b2, Wpt, bp, Wb, bb,
                                S12, Aarr, Carr);
    kQ<<<dim3(16, 16), 512, 0, stream>>>(S12, Aarr, Carr, Wb, noise,
                                         (float*)d_out);
}